// Round 1
// baseline (1474.464 us; speedup 1.0000x reference)
//
#include <hip/hip_runtime.h>
#include <hip/hip_bf16.h>

// Swin-V2 window attention, fused one-block-per-window. All I/O fp32.
// B=32, H=W=64, C=60, NH=6, hd=10, WS=7 -> pad 70, nw=10, 3200 windows x 49 tok.
//
// R10: occupancy push. LDS 51.7KB -> 37.6KB => 4 blocks/CU = 24 waves (was 18):
//  - s_q eliminated: q held in regs through P2, scattered into s_x rows after
//    the P2 barrier ([token][h*10+d] layout). P4 reads q from s_x and writes o
//    back to the SAME slots (1:1 thread->slot, race-free).
//  - s_v stride 12 -> 10 (5x ds_read_b64, 8B aligned). k stays 12 for b128.
//  - P4: deferred-max online softmax (single pass, no a[49] array) so the
//    kernel fits launch_bounds(384,6) <= 85 VGPR without scratch.
//  - P2 wave-pure mapping: waves {0,1}=q halves, {2,3}=k, {4,5}=v; 60 lanes
//    active each. q path runs two weight-half passes (w4[8]/w4[7]) to keep
//    qacc[25]+weights under the register cap. q halves overlap token 24
//    (both write the bit-identical value).

#define WSZ 7
#define NT 49
#define CH 60
#define IMG 64
#define LOG100F 4.605170185988092f

__global__ __launch_bounds__(384, 6)
void swin_win_attn(const float* __restrict__ x,
                   const float* __restrict__ qkv_w,
                   const float* __restrict__ qkv_b,
                   const float* __restrict__ logit_scale,
                   const float* __restrict__ proj_w,
                   const float* __restrict__ proj_b,
                   float* __restrict__ out)
{
    __shared__ __align__(16) float s_x[NT * CH];      // 2940 f: x -> q -> out
    __shared__ __align__(16) float s_k[6 * NT * 12];  // 3528 f, 48B rows (b128 x3)
    __shared__ __align__(16) float s_v[6 * NT * 10];  // 2940 f, 40B rows (b64 x5)
    // total 9408 floats = 37,632 B -> 4 blocks/CU

    const int tid  = threadIdx.x;
    const int lane = tid & 63;
    const int wv   = __builtin_amdgcn_readfirstlane(tid >> 6);
    const int w  = blockIdx.x;
    const int b  = w / 100;
    const int wy = (w / 10) % 10;
    const int wx = w % 10;
    const int row0 = wy * WSZ;
    const int col0 = wx * WSZ;

    // ---- Phase 1: stage x tile (49x60, rows 240B) + zero k pad words ----
    for (int idx = tid; idx < NT * 15; idx += 384) {
        int t = idx / 15, m = idx - t * 15;
        int r  = row0 + t / WSZ;
        int cc = col0 + t % WSZ;
        float4 v4 = make_float4(0.f, 0.f, 0.f, 0.f);
        if (r < IMG && cc < IMG)
            v4 = reinterpret_cast<const float4*>(x + ((b * IMG + r) * IMG + cc) * CH)[m];
        *reinterpret_cast<float4*>(s_x + t * CH + 4 * m) = v4;
    }
    if (tid < 6 * NT) {                 // k pad lanes (d=10,11) zeroed once
        s_k[tid * 12 + 10] = 0.f;
        s_k[tid * 12 + 11] = 0.f;
    }
    __syncthreads();

    // ---- Phase 2: qkv. Wave-pure: wv 0,1 = q halves; 2,3 = k; 4,5 = v. ----
    float qacc[25];                     // live only on q waves
    const int part  = wv >> 1;          // 0=q, 1=k, 2=v
    const int halfw = wv & 1;
    if (lane < 60) {
        const int c = part * 60 + lane;
        const int h = lane / 10, d = lane - 10 * (lane / 10);
        const float bias = qkv_b[c];
        const float4* wp = reinterpret_cast<const float4*>(qkv_w + c * CH);
        if (part == 0) {
            // q: accumulate 25 tokens in regs, two passes over the weight row
            const int t0 = halfw * 24;  // halves overlap token 24 (same value)
            #pragma unroll
            for (int tt = 0; tt < 25; ++tt) qacc[tt] = bias;
            {
                float4 w4[8];
                #pragma unroll
                for (int m = 0; m < 8; ++m) w4[m] = wp[m];
                #pragma unroll
                for (int tt = 0; tt < 25; ++tt) {
                    const float4* xr = reinterpret_cast<const float4*>(s_x + (t0 + tt) * CH);
                    float a = 0.f;
                    #pragma unroll
                    for (int m = 0; m < 8; ++m) {
                        float4 xv = xr[m];   // broadcast (same addr across wave)
                        a += xv.x * w4[m].x + xv.y * w4[m].y + xv.z * w4[m].z + xv.w * w4[m].w;
                    }
                    qacc[tt] += a;
                }
            }
            {
                float4 w4[7];
                #pragma unroll
                for (int m = 0; m < 7; ++m) w4[m] = wp[8 + m];
                #pragma unroll
                for (int tt = 0; tt < 25; ++tt) {
                    const float4* xr = reinterpret_cast<const float4*>(s_x + (t0 + tt) * CH) + 8;
                    float a = 0.f;
                    #pragma unroll
                    for (int m = 0; m < 7; ++m) {
                        float4 xv = xr[m];
                        a += xv.x * w4[m].x + xv.y * w4[m].y + xv.z * w4[m].z + xv.w * w4[m].w;
                    }
                    qacc[tt] += a;
                }
            }
        } else if (part == 1) {
            // k: write straight to LDS (stride 12)
            float4 w4[15];
            #pragma unroll
            for (int m = 0; m < 15; ++m) w4[m] = wp[m];
            const int t0 = halfw ? 25 : 0, t1 = halfw ? NT : 25;
            for (int t = t0; t < t1; ++t) {
                float a = bias;
                const float4* xr = reinterpret_cast<const float4*>(s_x + t * CH);
                #pragma unroll
                for (int m = 0; m < 15; ++m) {
                    float4 xv = xr[m];
                    a += xv.x * w4[m].x + xv.y * w4[m].y + xv.z * w4[m].z + xv.w * w4[m].w;
                }
                s_k[(h * NT + t) * 12 + d] = a;
            }
        } else {
            // v: write straight to LDS (stride 10)
            float4 w4[15];
            #pragma unroll
            for (int m = 0; m < 15; ++m) w4[m] = wp[m];
            const int t0 = halfw ? 25 : 0, t1 = halfw ? NT : 25;
            for (int t = t0; t < t1; ++t) {
                float a = bias;
                const float4* xr = reinterpret_cast<const float4*>(s_x + t * CH);
                #pragma unroll
                for (int m = 0; m < 15; ++m) {
                    float4 xv = xr[m];
                    a += xv.x * w4[m].x + xv.y * w4[m].y + xv.z * w4[m].z + xv.w * w4[m].w;
                }
                s_v[(h * NT + t) * 10 + d] = a;
            }
        }
    }
    __syncthreads();

    // ---- Phase 3: scatter q into s_x rows; L2-normalize k rows ----
    if (wv < 2 && lane < 60) {
        const int t0 = halfw * 24;
        #pragma unroll
        for (int tt = 0; tt < 25; ++tt)
            s_x[(t0 + tt) * CH + lane] = qacc[tt];   // [token][h*10+d]
    }
    if (tid < 6 * NT) {
        float* p = s_k + tid * 12;
        float ss = 0.f;
        #pragma unroll
        for (int d = 0; d < 10; ++d) ss += p[d] * p[d];
        float inv = 1.f / fmaxf(sqrtf(ss), 1e-12f);
        #pragma unroll
        for (int d = 0; d < 10; ++d) p[d] *= inv;
    }
    __syncthreads();

    // ---- Phase 4: attention; thread = (head,row); deferred-max online softmax ----
    if (tid < 6 * NT) {
        const int h = tid / NT, i = tid - h * NT;
        float scale = __expf(fminf(logit_scale[h], LOG100F));
        float q[10];
        {
            const float2* qp = reinterpret_cast<const float2*>(s_x + i * CH + h * 10);
            #pragma unroll
            for (int d2 = 0; d2 < 5; ++d2) { float2 t2 = qp[d2]; q[2*d2] = t2.x; q[2*d2+1] = t2.y; }
            float ss = 0.f;
            #pragma unroll
            for (int d = 0; d < 10; ++d) ss += q[d] * q[d];
            float inv = scale / fmaxf(sqrtf(ss), 1e-12f);  // fold scale into q
            #pragma unroll
            for (int d = 0; d < 10; ++d) q[d] *= inv;
        }
        float m = -1e30f, s = 0.f;
        float o[10];
        #pragma unroll
        for (int d = 0; d < 10; ++d) o[d] = 0.f;
        const float4* kb = reinterpret_cast<const float4*>(s_k + h * NT * 12);
        const float2* vb = reinterpret_cast<const float2*>(s_v + h * NT * 10);
        for (int j = 0; j < NT; ++j) {
            float4 k0 = kb[j * 3 + 0];
            float4 k1 = kb[j * 3 + 1];
            float4 k2 = kb[j * 3 + 2];   // .z,.w zeroed pads
            float a = q[0]*k0.x + q[1]*k0.y + q[2]*k0.z + q[3]*k0.w
                    + q[4]*k1.x + q[5]*k1.y + q[6]*k1.z + q[7]*k1.w
                    + q[8]*k2.x + q[9]*k2.y;
            if (a > m + 8.f) {           // rare: rescale running state
                float r = __expf(m - a);
                s *= r;
                #pragma unroll
                for (int d = 0; d < 10; ++d) o[d] *= r;
                m = a;
            }
            float p = __expf(a - m);     // bounded by e^8
            s += p;
            float2 v0 = vb[j * 5 + 0], v1 = vb[j * 5 + 1], v2 = vb[j * 5 + 2],
                   v3 = vb[j * 5 + 3], v4 = vb[j * 5 + 4];
            o[0] += p * v0.x; o[1] += p * v0.y; o[2] += p * v1.x; o[3] += p * v1.y;
            o[4] += p * v2.x; o[5] += p * v2.y; o[6] += p * v3.x; o[7] += p * v3.y;
            o[8] += p * v4.x; o[9] += p * v4.y;
        }
        float invs = 1.f / s;
        float* op = s_x + i * CH + h * 10;   // overwrite own q slots only
        #pragma unroll
        for (int d2 = 0; d2 < 5; ++d2)
            *reinterpret_cast<float2*>(op + 2 * d2) =
                make_float2(o[2*d2] * invs, o[2*d2+1] * invs);
    }
    __syncthreads();

    // ---- Phase 5: proj. lane<60 = out channel, W-row in regs, tokens over 6 waves ----
    if (lane < 60) {
        float4 w4[15];
        const float4* wp = reinterpret_cast<const float4*>(proj_w + lane * CH);
        #pragma unroll
        for (int m = 0; m < 15; ++m) w4[m] = wp[m];
        const float bias = proj_b[lane];
        for (int t = wv; t < NT; t += 6) {
            int r  = row0 + t / WSZ;
            int cc = col0 + t % WSZ;
            float a = bias;
            const float4* xr = reinterpret_cast<const float4*>(s_x + t * CH);
            #pragma unroll
            for (int m = 0; m < 15; ++m) {
                float4 xv = xr[m];                    // broadcast
                a += xv.x * w4[m].x + xv.y * w4[m].y
                   + xv.z * w4[m].z + xv.w * w4[m].w;
            }
            if (r < IMG && cc < IMG)
                out[((b * IMG + r) * IMG + cc) * CH + lane] = a;   // coalesced
        }
    }
}

extern "C" void kernel_launch(void* const* d_in, const int* in_sizes, int n_in,
                              void* d_out, int out_size, void* d_ws, size_t ws_size,
                              hipStream_t stream) {
    hipLaunchKernelGGL(swin_win_attn, dim3(3200), dim3(384), 0, stream,
                       (const float*)d_in[0], (const float*)d_in[1],
                       (const float*)d_in[2], (const float*)d_in[3],
                       (const float*)d_in[4], (const float*)d_in[5],
                       (float*)d_out);
}

// Round 2
// 650.647 us; speedup vs baseline: 2.2661x; 2.2661x over previous
//
#include <hip/hip_runtime.h>
#include <hip/hip_bf16.h>

// Swin-V2 window attention, fused one-block-per-window. All I/O fp32.
// B=32, H=W=64, C=60, NH=6, hd=10, WS=7 -> pad 70, nw=10, 3200 windows x 49 tok.
//
// R11: 4 blocks/CU (LDS 37.6KB) WITHOUT the R10 spill.
//  R10 post-mortem: qacc[25]+w4[] live together under the (384,6) cap made the
//  allocator dump arrays to scratch (FETCH 2.3GB, VALU 10%). Fix: phase-local
//  register sets, max array live across a barrier = qacc[9].
//  - P2a: k/v only (w4[15] live alone, R9-proven shape; no branch divergence,
//    k/v select via per-thread dst pointer+stride).
//  - P2b: q into qacc[9] (60ch x 6 token-groups), two weight-half passes
//    (w4[8]/w4[7]) -> ~50 live regs.
//  - P3: scatter qacc into s_x rows ([token][h*10+d]); normalize k.
//  - P4: deferred-max online softmax (reg-light, verified in R10 run).
//  - s_q eliminated (q lives in s_x); s_v stride 10; s_k stride 12 (b128 x3).

#define WSZ 7
#define NT 49
#define CH 60
#define IMG 64
#define LOG100F 4.605170185988092f

__global__ __launch_bounds__(384, 6)
void swin_win_attn(const float* __restrict__ x,
                   const float* __restrict__ qkv_w,
                   const float* __restrict__ qkv_b,
                   const float* __restrict__ logit_scale,
                   const float* __restrict__ proj_w,
                   const float* __restrict__ proj_b,
                   float* __restrict__ out)
{
    __shared__ __align__(16) float s_x[NT * CH];      // 2940 f: x -> q -> out
    __shared__ __align__(16) float s_k[6 * NT * 12];  // 3528 f, 48B rows (b128 x3)
    __shared__ __align__(16) float s_v[6 * NT * 10];  // 2940 f, 40B rows (b64 x5)
    // total 9408 floats = 37,632 B -> 4 blocks/CU = 24 waves

    const int tid  = threadIdx.x;
    const int lane = tid & 63;
    const int wv   = __builtin_amdgcn_readfirstlane(tid >> 6);
    const int w  = blockIdx.x;
    const int b  = w / 100;
    const int wy = (w / 10) % 10;
    const int wx = w % 10;
    const int row0 = wy * WSZ;
    const int col0 = wx * WSZ;

    // ---- Phase 1: stage x tile (49x60, rows 240B) + zero k pad words ----
    for (int idx = tid; idx < NT * 15; idx += 384) {
        int t = idx / 15, m = idx - t * 15;
        int r  = row0 + t / WSZ;
        int cc = col0 + t % WSZ;
        float4 v4 = make_float4(0.f, 0.f, 0.f, 0.f);
        if (r < IMG && cc < IMG)
            v4 = reinterpret_cast<const float4*>(x + ((b * IMG + r) * IMG + cc) * CH)[m];
        *reinterpret_cast<float4*>(s_x + t * CH + 4 * m) = v4;
    }
    if (tid < 6 * NT) {                 // k pad lanes (d=10,11) zeroed once
        s_k[tid * 12 + 10] = 0.f;
        s_k[tid * 12 + 11] = 0.f;
    }
    __syncthreads();

    // ---- Phase 2a: k/v. thread = (kv channel c120<120, token-third).
    //      w4[15] is the only big live set in this region. ----
    float qacc[9];                      // filled in P2b, scattered in P3
    if (tid < 360) {
        const int c120  = tid % 120;
        const int third = tid / 120;
        const int isv = (c120 >= 60) ? 1 : 0;
        const int cl  = c120 - 60 * isv;
        const int c   = 60 + 60 * isv + cl;          // 60..119 = k, 120..179 = v
        const int h = cl / 10, d = cl - 10 * (cl / 10);
        const float bias = qkv_b[c];
        const float4* wp = reinterpret_cast<const float4*>(qkv_w + c * CH);
        float4 w4[15];
        #pragma unroll
        for (int m = 0; m < 15; ++m) w4[m] = wp[m];
        float* dst = isv ? (s_v + (h * NT) * 10 + d) : (s_k + (h * NT) * 12 + d);
        const int stride = isv ? 10 : 12;
        const int t0 = third * 16;
        const int t1 = (third == 2) ? NT : t0 + 16;
        for (int t = t0; t < t1; ++t) {
            float a = bias;
            const float4* xr = reinterpret_cast<const float4*>(s_x + t * CH);
            #pragma unroll
            for (int m = 0; m < 15; ++m) {
                float4 xv = xr[m];       // broadcast (<=2 addrs per wave)
                a += xv.x * w4[m].x + xv.y * w4[m].y + xv.z * w4[m].z + xv.w * w4[m].w;
            }
            dst[t * stride] = a;
        }
    }

    // ---- Phase 2b: q into qacc[9]. thread = (q channel qc<60, group qg<6).
    //      Two weight-half passes keep live set ~= 9 + 32 regs. ----
    {
        const int qc = tid % 60;
        const int qg = tid / 60;
        if (tid < 360) {
            const int cnt = (qg == 5) ? 9 : 8;
            const int t0 = qg * 8;
            const float bias = qkv_b[qc];
            const float4* wp = reinterpret_cast<const float4*>(qkv_w + qc * CH);
            #pragma unroll
            for (int tt = 0; tt < 9; ++tt) qacc[tt] = bias;
            {
                float4 w4[8];
                #pragma unroll
                for (int m = 0; m < 8; ++m) w4[m] = wp[m];
                #pragma unroll
                for (int tt = 0; tt < 9; ++tt) {
                    if (tt < cnt) {
                        const float4* xr = reinterpret_cast<const float4*>(s_x + (t0 + tt) * CH);
                        float a = 0.f;
                        #pragma unroll
                        for (int m = 0; m < 8; ++m) {
                            float4 xv = xr[m];
                            a += xv.x * w4[m].x + xv.y * w4[m].y + xv.z * w4[m].z + xv.w * w4[m].w;
                        }
                        qacc[tt] += a;
                    }
                }
            }
            {
                float4 w4[7];
                #pragma unroll
                for (int m = 0; m < 7; ++m) w4[m] = wp[8 + m];
                #pragma unroll
                for (int tt = 0; tt < 9; ++tt) {
                    if (tt < cnt) {
                        const float4* xr = reinterpret_cast<const float4*>(s_x + (t0 + tt) * CH) + 8;
                        float a = 0.f;
                        #pragma unroll
                        for (int m = 0; m < 7; ++m) {
                            float4 xv = xr[m];
                            a += xv.x * w4[m].x + xv.y * w4[m].y + xv.z * w4[m].z + xv.w * w4[m].w;
                        }
                        qacc[tt] += a;
                    }
                }
            }
        }
    }
    __syncthreads();

    // ---- Phase 3: scatter q into s_x rows ([t][h*10+d]); normalize k rows ----
    if (tid < 360) {
        const int qc = tid % 60;
        const int qg = tid / 60;
        const int cnt = (qg == 5) ? 9 : 8;
        const int t0 = qg * 8;
        #pragma unroll
        for (int tt = 0; tt < 9; ++tt)
            if (tt < cnt) s_x[(t0 + tt) * CH + qc] = qacc[tt];
    }
    if (tid < 6 * NT) {
        float* p = s_k + tid * 12;
        float ss = 0.f;
        #pragma unroll
        for (int d = 0; d < 10; ++d) ss += p[d] * p[d];
        float inv = 1.f / fmaxf(sqrtf(ss), 1e-12f);
        #pragma unroll
        for (int d = 0; d < 10; ++d) p[d] *= inv;
    }
    __syncthreads();

    // ---- Phase 4: attention; thread = (head,row); deferred-max online softmax ----
    if (tid < 6 * NT) {
        const int h = tid / NT, i = tid - h * NT;
        float scale = __expf(fminf(logit_scale[h], LOG100F));
        float q[10];
        {
            const float2* qp = reinterpret_cast<const float2*>(s_x + i * CH + h * 10);
            #pragma unroll
            for (int d2 = 0; d2 < 5; ++d2) { float2 t2 = qp[d2]; q[2*d2] = t2.x; q[2*d2+1] = t2.y; }
            float ss = 0.f;
            #pragma unroll
            for (int d = 0; d < 10; ++d) ss += q[d] * q[d];
            float inv = scale / fmaxf(sqrtf(ss), 1e-12f);  // fold scale into q
            #pragma unroll
            for (int d = 0; d < 10; ++d) q[d] *= inv;
        }
        float m = -1e30f, s = 0.f;
        float o[10];
        #pragma unroll
        for (int d = 0; d < 10; ++d) o[d] = 0.f;
        const float4* kb = reinterpret_cast<const float4*>(s_k + h * NT * 12);
        const float2* vb = reinterpret_cast<const float2*>(s_v + h * NT * 10);
        for (int j = 0; j < NT; ++j) {
            float4 k0 = kb[j * 3 + 0];
            float4 k1 = kb[j * 3 + 1];
            float4 k2 = kb[j * 3 + 2];   // .z,.w zeroed pads
            float a = q[0]*k0.x + q[1]*k0.y + q[2]*k0.z + q[3]*k0.w
                    + q[4]*k1.x + q[5]*k1.y + q[6]*k1.z + q[7]*k1.w
                    + q[8]*k2.x + q[9]*k2.y;
            if (a > m + 8.f) {           // rare: rescale running state
                float r = __expf(m - a);
                s *= r;
                #pragma unroll
                for (int d = 0; d < 10; ++d) o[d] *= r;
                m = a;
            }
            float p = __expf(a - m);     // bounded by e^8
            s += p;
            float2 v0 = vb[j * 5 + 0], v1 = vb[j * 5 + 1], v2 = vb[j * 5 + 2],
                   v3 = vb[j * 5 + 3], v4 = vb[j * 5 + 4];
            o[0] += p * v0.x; o[1] += p * v0.y; o[2] += p * v1.x; o[3] += p * v1.y;
            o[4] += p * v2.x; o[5] += p * v2.y; o[6] += p * v3.x; o[7] += p * v3.y;
            o[8] += p * v4.x; o[9] += p * v4.y;
        }
        float invs = 1.f / s;
        float* op = s_x + i * CH + h * 10;   // overwrite own q slots only
        #pragma unroll
        for (int d2 = 0; d2 < 5; ++d2)
            *reinterpret_cast<float2*>(op + 2 * d2) =
                make_float2(o[2*d2] * invs, o[2*d2+1] * invs);
    }
    __syncthreads();

    // ---- Phase 5: proj. lane<60 = out channel, W-row in regs, tokens over 6 waves ----
    if (lane < 60) {
        float4 w4[15];
        const float4* wp = reinterpret_cast<const float4*>(proj_w + lane * CH);
        #pragma unroll
        for (int m = 0; m < 15; ++m) w4[m] = wp[m];
        const float bias = proj_b[lane];
        for (int t = wv; t < NT; t += 6) {
            int r  = row0 + t / WSZ;
            int cc = col0 + t % WSZ;
            float a = bias;
            const float4* xr = reinterpret_cast<const float4*>(s_x + t * CH);
            #pragma unroll
            for (int m = 0; m < 15; ++m) {
                float4 xv = xr[m];                    // broadcast
                a += xv.x * w4[m].x + xv.y * w4[m].y
                   + xv.z * w4[m].z + xv.w * w4[m].w;
            }
            if (r < IMG && cc < IMG)
                out[((b * IMG + r) * IMG + cc) * CH + lane] = a;   // coalesced
        }
    }
}

extern "C" void kernel_launch(void* const* d_in, const int* in_sizes, int n_in,
                              void* d_out, int out_size, void* d_ws, size_t ws_size,
                              hipStream_t stream) {
    hipLaunchKernelGGL(swin_win_attn, dim3(3200), dim3(384), 0, stream,
                       (const float*)d_in[0], (const float*)d_in[1],
                       (const float*)d_in[2], (const float*)d_in[3],
                       (const float*)d_in[4], (const float*)d_in[5],
                       (float*)d_out);
}